// Round 6
// baseline (233.053 us; speedup 1.0000x reference)
//
#include <hip/hip_runtime.h>
#include <math.h>

#define B 128
#define T 1024
#define H 256
#define L 16
#define INV_TEMP (1.0f/0.07f)
#define NEG_INF -1e30f

// ws layout (only seg<nseg regions are ever written/read -> no memset):
//   ws_pp   : float[B][4][L][H]   per-seg prototype partial sums   8 MB
//   ws_cntp : int[B][4][L]        per-seg label counts             32 KB
//   ws_dots : float[2][B][T][L]   per-H-half partial dots          16.8 MB

// ---------------------------------------------------------------------------
// Kernel 1 (v5, unchanged): GATHER formulation. Counting-sort tokens by label
// into LDS index lists, then each thread owns (label l, float4 column cs) and
// gathers the cnt[l] member rows from global into a register accumulator.
// grid = B * 4 segs * 4 chunks = 2048 blocks, 256 thr.  ~16 us measured-fit.
__global__ __launch_bounds__(256) void proto_kernel(
    const float* __restrict__ feat, const int* __restrict__ dlen,
    const int* __restrict__ labels, float* __restrict__ ws_pp,
    int* __restrict__ ws_cntp, float* __restrict__ out) {
  __shared__ int idx[L][256];   // 16 KB: token lists per label
  __shared__ int cnt[L];

  const int bx = blockIdx.x;
  if (bx == 0 && threadIdx.x == 0) out[0] = 0.f;   // replaces memset dispatch

  const int b = bx >> 4;
  const int seg = (bx >> 2) & 3;
  const int ch = bx & 3;          // 64-float chunk of H
  const int tid = threadIdx.x;

  const int len = dlen[b];
  if (seg * 256 >= len) return;   // uniform exit, before any barrier
  int segLen = len - seg * 256;
  if (segLen > 256) segLen = 256;

  if (tid < L) cnt[tid] = 0;
  __syncthreads();
  if (tid < segLen) {
    const int l = labels[(size_t)b * T + seg * 256 + tid];
    const int p = atomicAdd(&cnt[l], 1);   // 256 int atomics total: cheap
    idx[l][p] = tid;
  }
  __syncthreads();

  const int l = tid >> 4;         // owned label
  const int cs = tid & 15;        // owned float4 within the 64-float chunk
  const float4* fb4 = (const float4*)feat +
      ((size_t)b * T + seg * 256) * (H / 4) + ch * 16 + cs;

  const int c = cnt[l];
  float4 a = make_float4(0.f, 0.f, 0.f, 0.f);
  int i = 0;
  for (; i + 8 <= c; i += 8) {    // 8 independent loads in flight
    int t8[8];
#pragma unroll
    for (int u = 0; u < 8; ++u) t8[u] = idx[l][i + u];
    float4 f8[8];
#pragma unroll
    for (int u = 0; u < 8; ++u) f8[u] = fb4[(size_t)t8[u] * (H / 4)];
#pragma unroll
    for (int u = 0; u < 8; ++u) {
      a.x += f8[u].x; a.y += f8[u].y; a.z += f8[u].z; a.w += f8[u].w;
    }
  }
  for (; i < c; ++i) {
    const float4 f = fb4[(size_t)idx[l][i] * (H / 4)];
    a.x += f.x; a.y += f.y; a.z += f.z; a.w += f.w;
  }

  *(float4*)(ws_pp + (((size_t)b * 4 + seg) * L + l) * H + ch * 64 + cs * 4) = a;
  if (ch == 0 && tid < L) ws_cntp[(b * 4 + seg) * L + tid] = cnt[tid];
}

// ---------------------------------------------------------------------------
// Kernel 2 (v6): partial dots, back to the R0 shape that fits 16 FMA per
// wave-uniform ds_read_b128 (4 tokens share each pr read) -- the fused
// K=2 versions only reached 8 and measured ~15 us slower. Improvements over
// R0: grid doubled to B*2hh*2 token-halves = 512 blocks of 128 thr (2 blk/CU
// vs R0's 1), per-k-group uniform skip at 128-token granularity, float4
// prototype staging. Thread = token slots {q2*512 + k*128 + tid}, H-half hh.
__global__ __launch_bounds__(128) void dots_kernel(
    const float* __restrict__ feat, const int* __restrict__ dlen,
    const float* __restrict__ ws_pp, const int* __restrict__ ws_cntp,
    float* __restrict__ ws_dots) {
  __shared__ float pr[L * 128];   // 8 KB: this H-half of the prototypes
  __shared__ int cnts[L];

  const int bx = blockIdx.x;
  const int b = bx >> 2;
  const int hh = (bx >> 1) & 1;
  const int q2 = bx & 1;          // 512-token half
  const int tid = threadIdx.x;

  const int len = dlen[b];
  if (q2 * 512 >= len) return;    // uniform exit
  const int nseg = (len + 255) >> 8;
  // active 128-token groups in this half: ceil((len - q2*512)/128), clamp 4
  int kmax = (len - q2 * 512 + 127) >> 7;
  if (kmax > 4) kmax = 4;

  if (tid < L) {
    const int* cp = ws_cntp + b * 4 * L + tid;
    int c = 0;
    for (int s = 0; s < nseg; ++s) c += cp[s * L];
    cnts[tid] = c;
  }
  __syncthreads();

  // stage this half's prototypes: pr[l*128 + c] ; 512 float4, 4 iters
  const float4* gp4 = (const float4*)(ws_pp + (size_t)b * 4 * L * H);
  for (int i = tid; i < L * 32; i += 128) {
    const int l = i >> 5, c4 = i & 31;
    float4 s = gp4[(size_t)l * (H / 4) + hh * 32 + c4];
    for (int sg = 1; sg < nseg; ++sg) {
      const float4 t2 = gp4[((size_t)sg * L + l) * (H / 4) + hh * 32 + c4];
      s.x += t2.x; s.y += t2.y; s.z += t2.z; s.w += t2.w;
    }
    const int cn = cnts[l];
    const float inv = (cn > 0) ? 1.f / (float)cn : 0.f;
    ((float4*)pr)[i] = make_float4(s.x * inv, s.y * inv, s.z * inv, s.w * inv);
  }
  __syncthreads();

  const float4* fv[4];
#pragma unroll
  for (int k = 0; k < 4; ++k) {
    const int t = q2 * 512 + k * 128 + tid;
    fv[k] = (const float4*)(feat + ((size_t)b * T + t) * H + hh * 128);
  }

  float dot[4][L];
#pragma unroll
  for (int k = 0; k < 4; ++k)
#pragma unroll
    for (int l = 0; l < L; ++l) dot[k][l] = 0.f;

  for (int cb = 0; cb < 8; ++cb) {   // 8 x 16-float chunks of the 128-half
    float4 f[4][4];
#pragma unroll
    for (int k = 0; k < 4; ++k) {
      if (k < kmax) {                // block-uniform: skip dead token groups
#pragma unroll
        for (int q = 0; q < 4; ++q) f[k][q] = fv[k][cb * 4 + q];
      }
    }
#pragma unroll
    for (int q = 0; q < 4; ++q) {
#pragma unroll
      for (int l = 0; l < L; ++l) {
        const float4 p = *(const float4*)&pr[l * 128 + cb * 16 + q * 4];
#pragma unroll
        for (int k = 0; k < 4; ++k) {
          if (k < kmax) {            // 16 FMAs per pr read
            dot[k][l] += f[k][q].x * p.x + f[k][q].y * p.y +
                         f[k][q].z * p.z + f[k][q].w * p.w;
          }
        }
      }
    }
  }

#pragma unroll
  for (int k = 0; k < 4; ++k) {
    if (k < kmax) {                  // store whole group; loss masks t >= len
      const int t = q2 * 512 + k * 128 + tid;
      float4* d = (float4*)(ws_dots + (((size_t)hh * B + b) * T + t) * L);
#pragma unroll
      for (int q = 0; q < 4; ++q)
        d[q] = make_float4(dot[k][q * 4], dot[k][q * 4 + 1],
                           dot[k][q * 4 + 2], dot[k][q * 4 + 3]);
    }
  }
}

// ---------------------------------------------------------------------------
// Kernel 3: combine halves, log-softmax, masked mean. grid = B*4 = 512 blocks.
__global__ __launch_bounds__(256) void loss_kernel(
    const int* __restrict__ dlen, const int* __restrict__ labels,
    const int* __restrict__ ws_cntp, const float* __restrict__ ws_dots,
    float* __restrict__ out) {
  __shared__ int cnts[L];
  __shared__ float red[256];

  const int b = blockIdx.x >> 2;
  const int seg = blockIdx.x & 3;
  const int tid = threadIdx.x;

  const int len = dlen[b];
  if (seg * 256 >= len) return;        // contributes exactly 0
  const int nseg = (len + 255) >> 8;

  if (tid < L) {
    const int* cp = ws_cntp + b * 4 * L + tid;
    int c = 0;
    for (int s = 0; s < nseg; ++s) c += cp[s * L];
    cnts[tid] = c;
  }
  __syncthreads();

  const int t = seg * 256 + tid;
  float tok = 0.f;

  if (t < len) {
    const float4* d0 = (const float4*)(ws_dots + ((size_t)b * T + t) * L);
    const float4* d1 = (const float4*)((const float*)d0 + (size_t)B * T * L);
    float lg[L];
#pragma unroll
    for (int q = 0; q < 4; ++q) {
      const float4 a = d0[q];
      const float4 c = d1[q];
      lg[q * 4 + 0] = a.x + c.x;
      lg[q * 4 + 1] = a.y + c.y;
      lg[q * 4 + 2] = a.z + c.z;
      lg[q * 4 + 3] = a.w + c.w;
    }
#pragma unroll
    for (int l = 0; l < L; ++l)
      lg[l] = (cnts[l] > 0) ? lg[l] * INV_TEMP : NEG_INF;
    float m = lg[0];
#pragma unroll
    for (int l = 1; l < L; ++l) m = fmaxf(m, lg[l]);
    float se = 0.f;
#pragma unroll
    for (int l = 0; l < L; ++l) se += expf(lg[l] - m);
    const float lsp = m + logf(se);

    const int lab = labels[(size_t)b * T + t];
    float pos = 0.f;
#pragma unroll
    for (int l = 0; l < L; ++l) pos += (l == lab) ? lg[l] : 0.f;

    tok = lsp - pos;
  }

  red[tid] = tok;
  __syncthreads();
#pragma unroll
  for (int s = 128; s > 0; s >>= 1) {
    if (tid < s) red[tid] += red[tid + s];
    __syncthreads();
  }
  if (tid == 0) atomicAdd(out, red[0] / ((float)len * (float)B));
}

extern "C" void kernel_launch(void* const* d_in, const int* in_sizes, int n_in,
                              void* d_out, int out_size, void* d_ws, size_t ws_size,
                              hipStream_t stream) {
  const float* feat = (const float*)d_in[0];
  const int* dlen = (const int*)d_in[1];
  const int* labels = (const int*)d_in[2];
  float* out = (float*)d_out;

  float* ws_pp = (float*)d_ws;                           // B*4*L*H floats
  int* ws_cntp = (int*)(ws_pp + (size_t)B * 4 * L * H);  // B*4*L ints
  float* ws_dots = (float*)(ws_cntp + (size_t)B * 4 * L);// 2*B*T*L floats

  proto_kernel<<<B * 16, 256, 0, stream>>>(feat, dlen, labels, ws_pp,
                                           ws_cntp, out);
  dots_kernel<<<B * 4, 128, 0, stream>>>(feat, dlen, ws_pp, ws_cntp, ws_dots);
  loss_kernel<<<B * 4, 256, 0, stream>>>(dlen, labels, ws_cntp, ws_dots, out);
}